// Round 12
// baseline (3986.398 us; speedup 1.0000x reference)
//
#include <hip/hip_runtime.h>
#include <cstddef>

#define MDIM 512
#define DDIM 1024
#define BDIM 4096
#define NLAYERS 16

constexpr int BK = 32;
constexpr int BNP = 132;  // padded LDS row stride (words)

__device__ __forceinline__ float softf(float v, float t) {
  // relu(v-t) - relu(-v-t) == copysign(max(|v|-t,0), v)
  return copysignf(fmaxf(fabsf(v) - t, 0.0f), v);
}

// ---------------------------------------------------------------------------
// C = P(rows x K, row-major) @ B(K x 4096, row-major), fused epilogue.
// Bit-exact accumulation: per output element one fmaf chain, globally
// ascending k (BK=32 chunks asc., 8-k sub-chunks asc., kk asc.) — the same
// per-element chain as rounds 1/5 (absmax 0.2304688).
// Structure: A-operand NEVER touches LDS/VMEM-vector — wave-uniform scalar
// loads (s_load) feed fma directly from SGPRs. B staged in LDS; the ONLY
// per-lane memory op per kk is one ds_read_b64 feeding 16 fmas.
// Tile 32x128: 4 waves x 8 rows; lane -> 2 cols. Double-buffered, one
// barrier per chunk, global loads issued before compute.
// MODE 0: layer-0 A-kernel; MODE 1: scan A-kernel; MODE 2: B-kernel (soft-Z)
// ---------------------------------------------------------------------------
template <int MODE, int K, int MINW>
__global__ __launch_bounds__(256, MINW) void gemm_sg(
    const float* __restrict__ P, const float* __restrict__ Bm,
    const float* __restrict__ xg, const float* __restrict__ Ep,
    const float* __restrict__ Lp, const float* __restrict__ Zp,
    const float* __restrict__ beta1, const float* __restrict__ beta2,
    const float* __restrict__ beta3, const float* __restrict__ ss2,
    const float* __restrict__ apar, const float* __restrict__ apar1, int k,
    float* __restrict__ O0, float* __restrict__ O1, float* __restrict__ O2) {
  __shared__ __align__(16) float Bs[2][BK][BNP];

  const int tid = threadIdx.x;
  const int lane = tid & 63;
  const int w = __builtin_amdgcn_readfirstlane((int)(tid >> 6));
  const int m0 = blockIdx.x * 32, n0 = blockIdx.y * 128;
  const int r0 = m0 + w * 8;     // wave's 8 rows — uniform by construction
  const int c0 = n0 + lane * 2;  // thread's 2 cols

  const float* pA = P + (size_t)r0 * K;  // uniform base

  float acc[8][2];
#pragma unroll
  for (int r = 0; r < 8; ++r) {
    acc[r][0] = 0.0f;
    acc[r][1] = 0.0f;
  }

  // B staging: thread -> (row = tid>>3, 16-col chunk = (tid&7)*16)
  const int srow = tid >> 3, scol = (tid & 7) * 16;
  const float* gB = Bm + (size_t)srow * BDIM + n0 + scol;

  float4 rb[4];
  auto gload = [&](int k0) {
#pragma unroll
    for (int j = 0; j < 4; ++j)
      rb[j] = *reinterpret_cast<const float4*>(gB + (size_t)k0 * BDIM + j * 4);
  };
  auto stagewr = [&](int bb) {
#pragma unroll
    for (int j = 0; j < 4; ++j)
      *reinterpret_cast<float4*>(&Bs[bb][srow][scol + j * 4]) = rb[j];
  };
  auto comp = [&](int bb, int k0) {
#pragma unroll
    for (int s = 0; s < 4; ++s) {  // 8-k sub-chunks
      // wave-uniform scalar loads: 8 rows x 8 consecutive k -> s_load_dwordx8
      float a[8][8];
#pragma unroll
      for (int r = 0; r < 8; ++r)
#pragma unroll
        for (int q = 0; q < 8; ++q)
          a[r][q] = pA[(size_t)r * K + k0 + s * 8 + q];
#pragma unroll
      for (int q = 0; q < 8; ++q) {
        const int kk = s * 8 + q;
        const float2 b2 =
            *reinterpret_cast<const float2*>(&Bs[bb][kk][lane * 2]);
#pragma unroll
        for (int r = 0; r < 8; ++r) {
          acc[r][0] = fmaf(a[r][q], b2.x, acc[r][0]);
          acc[r][1] = fmaf(a[r][q], b2.y, acc[r][1]);
        }
      }
    }
  };

  constexpr int NS = K / BK;
  gload(0);
  stagewr(0);
  __syncthreads();
  int bb = 0;
#pragma unroll 1
  for (int t = 1; t < NS; ++t) {
    gload(t * BK);
    comp(bb, (t - 1) * BK);
    stagewr(bb ^ 1);  // other buffer — one barrier per chunk suffices
    __syncthreads();
    bb ^= 1;
  }
  comp(bb, (NS - 1) * BK);

  // ---- epilogue (expressions identical to rounds 1/5) ----
  const float b1v = (MODE == 2) ? 0.f : beta1[k];
  float b2v = 0.f, b3v = 0.f, s2v = 0.f, a1v = 0.f, ap = 0.f;
  if (MODE == 1) {
    b2v = beta2[k - 1];
    b3v = beta3[k - 1];
    s2v = ss2[k - 1];
    a1v = apar1[k - 1];
  }
  if (MODE == 2) ap = apar[k];

#pragma unroll
  for (int r = 0; r < 8; ++r) {
    const size_t off = (size_t)(r0 + r) * BDIM + c0;
    if (MODE == 2) {
      const float2 z2 = *reinterpret_cast<const float2*>(&Zp[off]);
      float2 o;
      o.x = softf(z2.x - acc[r][0], ap);
      o.y = softf(z2.y - acc[r][1], ap);
      *reinterpret_cast<float2*>(&O0[off]) = o;
    } else {
      const float2 e2 = *reinterpret_cast<const float2*>(&Ep[off]);
      const float2 l2 = *reinterpret_cast<const float2*>(&Lp[off]);
      const float2 x2 = *reinterpret_cast<const float2*>(&xg[off]);
      const float ev[2] = {e2.x, e2.y};
      const float lv[2] = {l2.x, l2.y};
      const float xv[2] = {x2.x, x2.y};
      float vo[2], eo[2], lo_[2];
#pragma unroll
      for (int j = 0; j < 2; ++j) {
        const float az = acc[r][j];
        if (MODE == 0) {
          const float t0 = az + ev[j] - xv[j];
          vo[j] = fmaf(b1v, t0, lv[j]);
          eo[j] = ev[j];
          lo_[j] = lv[j];
        } else {
          const float vv = fmaf(b2v, az + ev[j] - xv[j], lv[j]);
          const float en = softf(ev[j] - s2v * vv, a1v);
          const float tn_ = az + en - xv[j];
          const float ln = fmaf(b3v, tn_, lv[j]);
          eo[j] = en;
          lo_[j] = ln;
          vo[j] = fmaf(b1v, tn_, ln);
        }
      }
      float2 t2;
      t2.x = vo[0];
      t2.y = vo[1];
      *reinterpret_cast<float2*>(&O0[off]) = t2;
      t2.x = eo[0];
      t2.y = eo[1];
      *reinterpret_cast<float2*>(&O1[off]) = t2;
      t2.x = lo_[0];
      t2.y = lo_[1];
      *reinterpret_cast<float2*>(&O2[off]) = t2;
    }
  }
}

extern "C" void kernel_launch(void* const* d_in, const int* in_sizes, int n_in,
                              void* d_out, int out_size, void* d_ws,
                              size_t ws_size, hipStream_t stream) {
  (void)in_sizes;
  (void)n_in;
  (void)out_size;
  (void)ws_size;
  const float* x = (const float*)d_in[0];
  const float* A = (const float*)d_in[1];
  const float* W = (const float*)d_in[2];
  const float* Z0 = (const float*)d_in[3];
  const float* E0 = (const float*)d_in[4];
  const float* L0 = (const float*)d_in[5];
  const float* beta1 = (const float*)d_in[6];
  const float* beta2 = (const float*)d_in[7];
  const float* beta3 = (const float*)d_in[8];
  const float* ss2 = (const float*)d_in[9];
  const float* apar = (const float*)d_in[10];
  const float* apar1 = (const float*)d_in[11];

  constexpr size_t DB = (size_t)DDIM * BDIM;
  constexpr size_t MB = (size_t)MDIM * BDIM;
  float* Zall = (float*)d_out;
  float* Eall = Zall + (size_t)NLAYERS * DB;
  float* Lall = Eall + (size_t)NLAYERS * MB;
  float* Var = (float*)d_ws;  // MDIM*BDIM floats = 8 MiB

  const dim3 blk(256);
  const dim3 gA(MDIM / 32, BDIM / 128);  // (16, 32) =  512 blocks, 2/CU
  const dim3 gB(DDIM / 32, BDIM / 128);  // (32, 32) = 1024 blocks, 4/CU

  // layer 0
  gemm_sg<0, DDIM, 2><<<gA, blk, 0, stream>>>(
      A, Z0, x, E0, L0, nullptr, beta1, beta2, beta3, ss2, apar, apar1, 0, Var,
      Eall, Lall);
  gemm_sg<2, MDIM, 4><<<gB, blk, 0, stream>>>(
      W, Var, nullptr, nullptr, nullptr, Z0, beta1, beta2, beta3, ss2, apar,
      apar1, 0, Zall, nullptr, nullptr);
  // layers 1..15
  for (int k = 1; k < NLAYERS; ++k) {
    const float* Zp = Zall + (size_t)(k - 1) * DB;
    gemm_sg<1, DDIM, 2><<<gA, blk, 0, stream>>>(
        A, Zp, x, Eall + (size_t)(k - 1) * MB, Lall + (size_t)(k - 1) * MB,
        nullptr, beta1, beta2, beta3, ss2, apar, apar1, k, Var,
        Eall + (size_t)k * MB, Lall + (size_t)k * MB);
    gemm_sg<2, MDIM, 4><<<gB, blk, 0, stream>>>(
        W + (size_t)k * DDIM * MDIM, Var, nullptr, nullptr, nullptr, Zp, beta1,
        beta2, beta3, ss2, apar, apar1, k, Zall + (size_t)k * DB, nullptr,
        nullptr);
  }
}

// Round 13
// 2048.642 us; speedup vs baseline: 1.9459x; 1.9459x over previous
//
#include <hip/hip_runtime.h>
#include <cstddef>

#define MDIM 512
#define DDIM 1024
#define BDIM 4096
#define NLAYERS 16

constexpr int BK = 16;

__device__ __forceinline__ float softf(float v, float t) {
  // relu(v-t) - relu(-v-t) == copysign(max(|v|-t,0), v)
  return copysignf(fmaxf(fabsf(v) - t, 0.0f), v);
}

// ---------------------------------------------------------------------------
// C = P(rows x K, row-major) @ B(K x 4096, row-major), fused epilogue.
// Bit-exact accumulation: per output element one fmaf chain, k ascending
// (BK=16 chunks ascending, kk ascending) — identical chain to rounds 1/5
// (absmax 0.2304688). Structure = round-5 (proven best, 2052 us) with ONE
// change: B-fragment columns split into groups {g*64 + tn*4} so both float4
// LDS reads are 2-way bank-aliased (free) instead of 4-way (1.58x) — the
// 4-way conflict sat on the binding LDS pipe of the B-GEMM.
// MODE 0: layer-0 A-kernel; MODE 1: scan A-kernel; MODE 2: B-kernel (soft-Z)
// ---------------------------------------------------------------------------
template <int MODE, int K, int BN>
__global__ __launch_bounds__(256) void gemm_f32(
    const float* __restrict__ P, const float* __restrict__ Bm,
    const float* __restrict__ xg, const float* __restrict__ Ep,
    const float* __restrict__ Lp, const float* __restrict__ Zp,
    const float* __restrict__ beta1, const float* __restrict__ beta2,
    const float* __restrict__ beta3, const float* __restrict__ ss2,
    const float* __restrict__ apar, const float* __restrict__ apar1, int k,
    float* __restrict__ O0, float* __restrict__ O1, float* __restrict__ O2) {
  constexpr int NG = BN / 64;  // column groups of 4 (1 or 2)
  __shared__ __align__(16) float As[2][BK][68];  // padded
  __shared__ __align__(16) float Bs[2][BK][BN];

  const int tid = threadIdx.x;
  const int tn = tid & 15, tm = tid >> 4;  // micro-tile coords
  const int m0 = blockIdx.x * 64, n0 = blockIdx.y * BN;

  float acc[4][NG][4];
#pragma unroll
  for (int r = 0; r < 4; ++r)
#pragma unroll
    for (int g = 0; g < NG; ++g)
#pragma unroll
      for (int j = 0; j < 4; ++j) acc[r][g][j] = 0.0f;

  // A staging map: thread -> (row ar, k-chunk akc of 4)
  const int ar = tid >> 2, akc = tid & 3;
  const float* gA = P + (size_t)(m0 + ar) * K + akc * 4;
  // B staging map
  const int br = (NG == 1) ? (tid >> 4) : (tid >> 5);
  const int bc = (NG == 1) ? (tid & 15) : (tid & 31);
  const float* gB = Bm + (size_t)br * BDIM + n0 + bc * 4;

  float4 ra, rb0, rb1;
  auto gload = [&](int k0) {
    ra = *reinterpret_cast<const float4*>(gA + (size_t)k0);
    rb0 = *reinterpret_cast<const float4*>(gB + (size_t)k0 * BDIM);
    if (NG == 2)
      rb1 = *reinterpret_cast<const float4*>(gB + (size_t)(k0 + 8) * BDIM);
  };
  auto stagewr = [&](int bb) {
    As[bb][akc * 4 + 0][ar] = ra.x;
    As[bb][akc * 4 + 1][ar] = ra.y;
    As[bb][akc * 4 + 2][ar] = ra.z;
    As[bb][akc * 4 + 3][ar] = ra.w;
    *reinterpret_cast<float4*>(&Bs[bb][br][bc * 4]) = rb0;
    if (NG == 2) *reinterpret_cast<float4*>(&Bs[bb][br + 8][bc * 4]) = rb1;
  };
  auto comp = [&](int bb) {
#pragma unroll
    for (int kk = 0; kk < BK; ++kk) {
      const float4 a4 = *reinterpret_cast<const float4*>(&As[bb][kk][tm * 4]);
      const float a[4] = {a4.x, a4.y, a4.z, a4.w};
      float bv[NG][4];
#pragma unroll
      for (int g = 0; g < NG; ++g)
        *reinterpret_cast<float4*>(&bv[g][0]) =
            *reinterpret_cast<const float4*>(&Bs[bb][kk][g * 64 + tn * 4]);
#pragma unroll
      for (int r = 0; r < 4; ++r)
#pragma unroll
        for (int g = 0; g < NG; ++g)
#pragma unroll
          for (int j = 0; j < 4; ++j)
            acc[r][g][j] = fmaf(a[r], bv[g][j], acc[r][g][j]);
    }
  };

  constexpr int NS = K / BK;
  gload(0);
  stagewr(0);
  __syncthreads();
  int bb = 0;
#pragma unroll 1
  for (int t = 1; t < NS; ++t) {
    gload(t * BK);
    comp(bb);         // reads buffer bb
    stagewr(bb ^ 1);  // writes the other buffer — one barrier suffices
    __syncthreads();
    bb ^= 1;
  }
  comp(bb);

  // ---- epilogue (expressions identical to rounds 1/5) ----
  const float b1v = (MODE == 2) ? 0.f : beta1[k];
  float b2v = 0.f, b3v = 0.f, s2v = 0.f, a1v = 0.f, ap = 0.f;
  if (MODE == 1) {
    b2v = beta2[k - 1];
    b3v = beta3[k - 1];
    s2v = ss2[k - 1];
    a1v = apar1[k - 1];
  }
  if (MODE == 2) ap = apar[k];

#pragma unroll
  for (int r = 0; r < 4; ++r) {
    const int row = m0 + tm * 4 + r;
#pragma unroll
    for (int g = 0; g < NG; ++g) {
      const int col = n0 + g * 64 + tn * 4;
      const size_t off = (size_t)row * BDIM + col;
      if (MODE == 2) {
        const float4 z4 = *reinterpret_cast<const float4*>(&Zp[off]);
        const float z[4] = {z4.x, z4.y, z4.z, z4.w};
        float4 o;
        float* op = reinterpret_cast<float*>(&o);
#pragma unroll
        for (int j = 0; j < 4; ++j) op[j] = softf(z[j] - acc[r][g][j], ap);
        *reinterpret_cast<float4*>(&O0[off]) = o;
      } else {
        float ev[4], lv[4], xv[4];
        *reinterpret_cast<float4*>(&ev[0]) =
            *reinterpret_cast<const float4*>(&Ep[off]);
        *reinterpret_cast<float4*>(&lv[0]) =
            *reinterpret_cast<const float4*>(&Lp[off]);
        *reinterpret_cast<float4*>(&xv[0]) =
            *reinterpret_cast<const float4*>(&xg[off]);
        float vo[4], eo[4], lo_[4];
#pragma unroll
        for (int j = 0; j < 4; ++j) {
          const float az = acc[r][g][j];
          if (MODE == 0) {
            const float t0 = az + ev[j] - xv[j];
            vo[j] = fmaf(b1v, t0, lv[j]);
            eo[j] = ev[j];
            lo_[j] = lv[j];
          } else {
            const float vv = fmaf(b2v, az + ev[j] - xv[j], lv[j]);
            const float en = softf(ev[j] - s2v * vv, a1v);
            const float tn_ = az + en - xv[j];
            const float ln = fmaf(b3v, tn_, lv[j]);
            eo[j] = en;
            lo_[j] = ln;
            vo[j] = fmaf(b1v, tn_, ln);
          }
        }
        *reinterpret_cast<float4*>(&O0[off]) =
            *reinterpret_cast<const float4*>(&vo[0]);
        *reinterpret_cast<float4*>(&O1[off]) =
            *reinterpret_cast<const float4*>(&eo[0]);
        *reinterpret_cast<float4*>(&O2[off]) =
            *reinterpret_cast<const float4*>(&lo_[0]);
      }
    }
  }
}

extern "C" void kernel_launch(void* const* d_in, const int* in_sizes, int n_in,
                              void* d_out, int out_size, void* d_ws,
                              size_t ws_size, hipStream_t stream) {
  (void)in_sizes;
  (void)n_in;
  (void)out_size;
  (void)ws_size;
  const float* x = (const float*)d_in[0];
  const float* A = (const float*)d_in[1];
  const float* W = (const float*)d_in[2];
  const float* Z0 = (const float*)d_in[3];
  const float* E0 = (const float*)d_in[4];
  const float* L0 = (const float*)d_in[5];
  const float* beta1 = (const float*)d_in[6];
  const float* beta2 = (const float*)d_in[7];
  const float* beta3 = (const float*)d_in[8];
  const float* ss2 = (const float*)d_in[9];
  const float* apar = (const float*)d_in[10];
  const float* apar1 = (const float*)d_in[11];

  constexpr size_t DB = (size_t)DDIM * BDIM;
  constexpr size_t MB = (size_t)MDIM * BDIM;
  float* Zall = (float*)d_out;
  float* Eall = Zall + (size_t)NLAYERS * DB;
  float* Lall = Eall + (size_t)NLAYERS * MB;
  float* Var = (float*)d_ws;  // MDIM*BDIM floats = 8 MiB

  const dim3 blk(256);
  const dim3 gA(MDIM / 64, BDIM / 64);   // 8 x 64  = 512 blocks (BN=64)
  const dim3 gB(DDIM / 64, BDIM / 128);  // 16 x 32 = 512 blocks (BN=128)

  // layer 0
  gemm_f32<0, DDIM, 64><<<gA, blk, 0, stream>>>(
      A, Z0, x, E0, L0, nullptr, beta1, beta2, beta3, ss2, apar, apar1, 0, Var,
      Eall, Lall);
  gemm_f32<2, MDIM, 128><<<gB, blk, 0, stream>>>(
      W, Var, nullptr, nullptr, nullptr, Z0, beta1, beta2, beta3, ss2, apar,
      apar1, 0, Zall, nullptr, nullptr);
  // layers 1..15
  for (int k = 1; k < NLAYERS; ++k) {
    const float* Zp = Zall + (size_t)(k - 1) * DB;
    gemm_f32<1, DDIM, 64><<<gA, blk, 0, stream>>>(
        A, Zp, x, Eall + (size_t)(k - 1) * MB, Lall + (size_t)(k - 1) * MB,
        nullptr, beta1, beta2, beta3, ss2, apar, apar1, k,
        Var, Eall + (size_t)k * MB, Lall + (size_t)k * MB);
    gemm_f32<2, MDIM, 128><<<gB, blk, 0, stream>>>(
        W + (size_t)k * DDIM * MDIM, Var, nullptr, nullptr, nullptr, Zp, beta1,
        beta2, beta3, ss2, apar, apar1, k, Zall + (size_t)k * DB, nullptr,
        nullptr);
  }
}

// Round 14
// 1987.233 us; speedup vs baseline: 2.0060x; 1.0309x over previous
//
#include <hip/hip_runtime.h>
#include <cstddef>

#define MDIM 512
#define DDIM 1024
#define BDIM 4096
#define NLAYERS 16

constexpr int BK = 16;

typedef float f32x2 __attribute__((ext_vector_type(2)));

__device__ __forceinline__ float softf(float v, float t) {
  // relu(v-t) - relu(-v-t) == copysign(max(|v|-t,0), v)
  return copysignf(fmaxf(fabsf(v) - t, 0.0f), v);
}

// ---------------------------------------------------------------------------
// C = P(rows x K, row-major) @ B(K x 4096, row-major), fused epilogue.
// Bit-exact accumulation: per output element one fma chain, k ascending
// (BK=16 chunks ascending, kk ascending) — identical per-element chain to
// rounds 1/5/13 (absmax 0.2304688). v_pk_fma_f32 = two INDEPENDENT IEEE
// fmas, so packing adjacent columns changes no per-element chain.
// Structure = round-13 (2048 us, fma-issue-bound at 65% of the 103 TF scalar
// ceiling) with ONE change: packed f32x2 accumulation halves the fma
// instruction stream (157 TF packed path).
// MODE 0: layer-0 A-kernel; MODE 1: scan A-kernel; MODE 2: B-kernel (soft-Z)
// ---------------------------------------------------------------------------
template <int MODE, int K, int BN>
__global__ __launch_bounds__(256) void gemm_f32(
    const float* __restrict__ P, const float* __restrict__ Bm,
    const float* __restrict__ xg, const float* __restrict__ Ep,
    const float* __restrict__ Lp, const float* __restrict__ Zp,
    const float* __restrict__ beta1, const float* __restrict__ beta2,
    const float* __restrict__ beta3, const float* __restrict__ ss2,
    const float* __restrict__ apar, const float* __restrict__ apar1, int k,
    float* __restrict__ O0, float* __restrict__ O1, float* __restrict__ O2) {
  constexpr int NG = BN / 64;  // column groups of 4 (1 or 2)
  __shared__ __align__(16) float As[2][BK][68];  // padded
  __shared__ __align__(16) float Bs[2][BK][BN];

  const int tid = threadIdx.x;
  const int tn = tid & 15, tm = tid >> 4;  // micro-tile coords
  const int m0 = blockIdx.x * 64, n0 = blockIdx.y * BN;

  f32x2 acc[4][NG][2];  // [row][col-group][pair]: cols g*64+tn*4 + 2*p + h
#pragma unroll
  for (int r = 0; r < 4; ++r)
#pragma unroll
    for (int g = 0; g < NG; ++g)
#pragma unroll
      for (int p = 0; p < 2; ++p) acc[r][g][p] = (f32x2)(0.0f);

  // A staging map: thread -> (row ar, k-chunk akc of 4)
  const int ar = tid >> 2, akc = tid & 3;
  const float* gA = P + (size_t)(m0 + ar) * K + akc * 4;
  // B staging map
  const int br = (NG == 1) ? (tid >> 4) : (tid >> 5);
  const int bc = (NG == 1) ? (tid & 15) : (tid & 31);
  const float* gB = Bm + (size_t)br * BDIM + n0 + bc * 4;

  float4 ra, rb0, rb1;
  auto gload = [&](int k0) {
    ra = *reinterpret_cast<const float4*>(gA + (size_t)k0);
    rb0 = *reinterpret_cast<const float4*>(gB + (size_t)k0 * BDIM);
    if (NG == 2)
      rb1 = *reinterpret_cast<const float4*>(gB + (size_t)(k0 + 8) * BDIM);
  };
  auto stagewr = [&](int bb) {
    As[bb][akc * 4 + 0][ar] = ra.x;
    As[bb][akc * 4 + 1][ar] = ra.y;
    As[bb][akc * 4 + 2][ar] = ra.z;
    As[bb][akc * 4 + 3][ar] = ra.w;
    *reinterpret_cast<float4*>(&Bs[bb][br][bc * 4]) = rb0;
    if (NG == 2) *reinterpret_cast<float4*>(&Bs[bb][br + 8][bc * 4]) = rb1;
  };
  auto comp = [&](int bb) {
#pragma unroll
    for (int kk = 0; kk < BK; ++kk) {
      const float4 a4 = *reinterpret_cast<const float4*>(&As[bb][kk][tm * 4]);
      const float a[4] = {a4.x, a4.y, a4.z, a4.w};
      f32x2 bv[NG][2];
#pragma unroll
      for (int g = 0; g < NG; ++g) {
        bv[g][0] =
            *reinterpret_cast<const f32x2*>(&Bs[bb][kk][g * 64 + tn * 4]);
        bv[g][1] =
            *reinterpret_cast<const f32x2*>(&Bs[bb][kk][g * 64 + tn * 4 + 2]);
      }
#pragma unroll
      for (int r = 0; r < 4; ++r) {
        const f32x2 av = {a[r], a[r]};
#pragma unroll
        for (int g = 0; g < NG; ++g)
#pragma unroll
          for (int p = 0; p < 2; ++p)
            acc[r][g][p] = __builtin_elementwise_fma(av, bv[g][p], acc[r][g][p]);
      }
    }
  };

  constexpr int NS = K / BK;
  gload(0);
  stagewr(0);
  __syncthreads();
  int bb = 0;
#pragma unroll 1
  for (int t = 1; t < NS; ++t) {
    gload(t * BK);
    comp(bb);         // reads buffer bb
    stagewr(bb ^ 1);  // writes the other buffer — one barrier suffices
    __syncthreads();
    bb ^= 1;
  }
  comp(bb);

  // ---- epilogue (expressions identical to rounds 1/5/13) ----
  const float b1v = (MODE == 2) ? 0.f : beta1[k];
  float b2v = 0.f, b3v = 0.f, s2v = 0.f, a1v = 0.f, ap = 0.f;
  if (MODE == 1) {
    b2v = beta2[k - 1];
    b3v = beta3[k - 1];
    s2v = ss2[k - 1];
    a1v = apar1[k - 1];
  }
  if (MODE == 2) ap = apar[k];

#pragma unroll
  for (int r = 0; r < 4; ++r) {
    const int row = m0 + tm * 4 + r;
#pragma unroll
    for (int g = 0; g < NG; ++g) {
      const int col = n0 + g * 64 + tn * 4;
      const size_t off = (size_t)row * BDIM + col;
      float av[4];
#pragma unroll
      for (int j = 0; j < 4; ++j) av[j] = acc[r][g][j >> 1][j & 1];
      if (MODE == 2) {
        const float4 z4 = *reinterpret_cast<const float4*>(&Zp[off]);
        const float z[4] = {z4.x, z4.y, z4.z, z4.w};
        float4 o;
        float* op = reinterpret_cast<float*>(&o);
#pragma unroll
        for (int j = 0; j < 4; ++j) op[j] = softf(z[j] - av[j], ap);
        *reinterpret_cast<float4*>(&O0[off]) = o;
      } else {
        float ev[4], lv[4], xv[4];
        *reinterpret_cast<float4*>(&ev[0]) =
            *reinterpret_cast<const float4*>(&Ep[off]);
        *reinterpret_cast<float4*>(&lv[0]) =
            *reinterpret_cast<const float4*>(&Lp[off]);
        *reinterpret_cast<float4*>(&xv[0]) =
            *reinterpret_cast<const float4*>(&xg[off]);
        float vo[4], eo[4], lo_[4];
#pragma unroll
        for (int j = 0; j < 4; ++j) {
          const float az = av[j];
          if (MODE == 0) {
            const float t0 = az + ev[j] - xv[j];
            vo[j] = fmaf(b1v, t0, lv[j]);
            eo[j] = ev[j];
            lo_[j] = lv[j];
          } else {
            const float vv = fmaf(b2v, az + ev[j] - xv[j], lv[j]);
            const float en = softf(ev[j] - s2v * vv, a1v);
            const float tn_ = az + en - xv[j];
            const float ln = fmaf(b3v, tn_, lv[j]);
            eo[j] = en;
            lo_[j] = ln;
            vo[j] = fmaf(b1v, tn_, ln);
          }
        }
        *reinterpret_cast<float4*>(&O0[off]) =
            *reinterpret_cast<const float4*>(&vo[0]);
        *reinterpret_cast<float4*>(&O1[off]) =
            *reinterpret_cast<const float4*>(&eo[0]);
        *reinterpret_cast<float4*>(&O2[off]) =
            *reinterpret_cast<const float4*>(&lo_[0]);
      }
    }
  }
}

extern "C" void kernel_launch(void* const* d_in, const int* in_sizes, int n_in,
                              void* d_out, int out_size, void* d_ws,
                              size_t ws_size, hipStream_t stream) {
  (void)in_sizes;
  (void)n_in;
  (void)out_size;
  (void)ws_size;
  const float* x = (const float*)d_in[0];
  const float* A = (const float*)d_in[1];
  const float* W = (const float*)d_in[2];
  const float* Z0 = (const float*)d_in[3];
  const float* E0 = (const float*)d_in[4];
  const float* L0 = (const float*)d_in[5];
  const float* beta1 = (const float*)d_in[6];
  const float* beta2 = (const float*)d_in[7];
  const float* beta3 = (const float*)d_in[8];
  const float* ss2 = (const float*)d_in[9];
  const float* apar = (const float*)d_in[10];
  const float* apar1 = (const float*)d_in[11];

  constexpr size_t DB = (size_t)DDIM * BDIM;
  constexpr size_t MB = (size_t)MDIM * BDIM;
  float* Zall = (float*)d_out;
  float* Eall = Zall + (size_t)NLAYERS * DB;
  float* Lall = Eall + (size_t)NLAYERS * MB;
  float* Var = (float*)d_ws;  // MDIM*BDIM floats = 8 MiB

  const dim3 blk(256);
  const dim3 gA(MDIM / 64, BDIM / 64);   // 8 x 64  = 512 blocks (BN=64)
  const dim3 gB(DDIM / 64, BDIM / 128);  // 16 x 32 = 512 blocks (BN=128)

  // layer 0
  gemm_f32<0, DDIM, 64><<<gA, blk, 0, stream>>>(
      A, Z0, x, E0, L0, nullptr, beta1, beta2, beta3, ss2, apar, apar1, 0, Var,
      Eall, Lall);
  gemm_f32<2, MDIM, 128><<<gB, blk, 0, stream>>>(
      W, Var, nullptr, nullptr, nullptr, Z0, beta1, beta2, beta3, ss2, apar,
      apar1, 0, Zall, nullptr, nullptr);
  // layers 1..15
  for (int k = 1; k < NLAYERS; ++k) {
    const float* Zp = Zall + (size_t)(k - 1) * DB;
    gemm_f32<1, DDIM, 64><<<gA, blk, 0, stream>>>(
        A, Zp, x, Eall + (size_t)(k - 1) * MB, Lall + (size_t)(k - 1) * MB,
        nullptr, beta1, beta2, beta3, ss2, apar, apar1, k,
        Var, Eall + (size_t)k * MB, Lall + (size_t)k * MB);
    gemm_f32<2, MDIM, 128><<<gB, blk, 0, stream>>>(
        W + (size_t)k * DDIM * MDIM, Var, nullptr, nullptr, nullptr, Zp, beta1,
        beta2, beta3, ss2, apar, apar1, k, Zall + (size_t)k * DB, nullptr,
        nullptr);
  }
}